// Round 6
// baseline (113.680 us; speedup 1.0000x reference)
//
#include <hip/hip_runtime.h>
#include <stdint.h>

#define IN_F   4096
#define OUT_F  768
#define NB     8
#define BATCH  4096
#define WCOLS  (OUT_F*NB)   // 6144

typedef short  bf16x8  __attribute__((ext_vector_type(8)));
typedef float  f32x4   __attribute__((ext_vector_type(4)));

__device__ __forceinline__ unsigned short f2bf(float f){
    union { float f; uint32_t u; } v; v.f = f;
    uint32_t u = v.u;
    u += 0x7FFFu + ((u >> 16) & 1u);   // round-to-nearest-even
    return (unsigned short)(u >> 16);
}

__device__ __forceinline__ float bf2f(unsigned short u){
    union { uint32_t q; float f; } v; v.q = ((uint32_t)u) << 16;
    return v.f;
}

__device__ __forceinline__ void gload16(const void* g, void* l){
    __builtin_amdgcn_global_load_lds(
        (const __attribute__((address_space(1))) unsigned int*)g,
        (__attribute__((address_space(3))) unsigned int*)l, 16, 0, 0);
}

// counted vmcnt wait + scheduler fence (rule #18)
#define WAITV(n) do {                                                   \
    asm volatile("s_waitcnt vmcnt(" #n ")" ::: "memory");               \
    __builtin_amdgcn_sched_barrier(0);                                  \
} while (0)

#define LGKM0() asm volatile("s_waitcnt lgkmcnt(0)" ::: "memory")

// ------- kernel 1: merged weight-decode (-> bt, polp) + true_sum decode -----
__launch_bounds__(256)
__global__ void decode_all(const float* __restrict__ w,
                           const float* __restrict__ ts,
                           unsigned short* __restrict__ bt,
                           unsigned short* __restrict__ isum,
                           float* __restrict__ polp){
    __shared__ unsigned short tile[64][70];
    __shared__ float part[4];
    const int tid = threadIdx.x;
    const int bid = blockIdx.x;
    if (bid < 768){
        // ---- sigmoid-decode weight -> int_weights^T (bf16) ----
        const int k0 = (bid & 63) * 64;
        const int n0 = (bid >> 6) * 64;
        const int j     = tid & 63;
        const int ibase = (tid >> 6) * 16;
        float pol = 0.f;
        #pragma unroll 4
        for (int r = 0; r < 16; ++r){
            int i = ibase + r;
            const float4* src = (const float4*)(w + (size_t)(k0+i)*WCOLS + (size_t)(n0+j)*8);
            float4 a = src[0], b = src[1];
            float x[8] = {a.x,a.y,a.z,a.w,b.x,b.y,b.z,b.w};
            float p[8];
            #pragma unroll
            for (int q = 0; q < 8; ++q){
                p[q] = 1.f / (1.f + __expf(-x[q]));
                pol += p[q] * (1.f - p[q]);
            }
            float iw = p[0] + 2.f*p[1] + 4.f*p[2] + 8.f*p[3]
                     + 16.f*p[4] + 32.f*p[5] + 64.f*p[6] - 128.f*p[7];
            tile[j][i] = f2bf(iw);
        }
        #pragma unroll
        for (int off = 32; off; off >>= 1) pol += __shfl_down(pol, off);
        if ((tid & 63) == 0) part[tid >> 6] = pol;
        __syncthreads();
        const int nrow = tid >> 4;
        const int kb   = (tid & 15) * 4;
        #pragma unroll
        for (int q = 0; q < 4; ++q){
            int n = nrow + q*16;
            uint2 v;
            v.x = *(const unsigned int*)&tile[n][kb];
            v.y = *(const unsigned int*)&tile[n][kb+2];
            *(uint2*)(bt + (size_t)(n0+n)*IN_F + k0 + kb) = v;
        }
        if (tid == 0) polp[bid] = part[0]+part[1]+part[2]+part[3];
    } else {
        // ---- true_sum bits -> isum (bf16, [BATCH][OUT_F]) ----
        const int b = bid - 768;          // 0..2047
        #pragma unroll
        for (int k = 0; k < 6; ++k){
            int e = b * 1536 + k * 256 + tid;
            const float4* q = (const float4*)(ts + (size_t)e * 8);
            float4 x = q[0], y = q[1];
            float v = x.x + 2.f*x.y + 4.f*x.z + 8.f*x.w
                    + 16.f*y.x + 32.f*y.y + 64.f*y.z - 128.f*y.w;
            isum[e] = f2bf(v);
        }
    }
}

// ------- kernel 2: GEMM; A-cast fused into A-stager waves -------------------
#define BM 64
#define BN 96
#define BK 64
#define NT (IN_F/BK)               // 64 K-steps
#define A_STRIDE 144               // 128B bf16 row + 16B pad (conflict-free)
#define ABYTES (BM*A_STRIDE)       // 9216
#define BBYTES (BN*BK*2)           // 12288
#define BUFB   (ABYTES+BBYTES)     // 21504

__launch_bounds__(512, 4)
__global__ void gemm_loss(const float* __restrict__ lat,
                          const unsigned short* __restrict__ bt,
                          const unsigned short* __restrict__ isum,
                          float* __restrict__ lossp){
    __shared__ __align__(16) char smem[3*BUFB];   // 63 KB -> 2 blocks/CU
    __shared__ float part[8];
    const int tid = threadIdx.x;
    const int w   = tid >> 6;
    const int l   = tid & 63;
    const int s   = l & 15, g = l >> 4;
    const int bid = blockIdx.x;
    const int m0  = (bid & 63) * BM;   // m-major: same-m blocks share an XCD
    const int n0  = (bid >> 6) * BN;

    char* r0 = smem;             // tile t (ready)
    char* r1 = smem + BUFB;      // tile t+1 (in flight)
    char* r2 = smem + 2*BUFB;    // tile t+2 (stage target)
    #define ROT() do { char* _t = r0; r0 = r1; r1 = r2; r2 = _t; } while (0)

    float local = 0.f;

    if (w < 4){
        // ================= consumer waves: ds_read + MFMA ===================
        const int wr = w >> 1, wc = w & 1;     // 2x2, wave tile 32x48
        f32x4 accv[2][3];
        #pragma unroll
        for (int m = 0; m < 2; ++m)
            #pragma unroll
            for (int n = 0; n < 3; ++n)
                accv[m][n] = (f32x4){0.f,0.f,0.f,0.f};

        #define COMPUTE(base) do {                                             \
            char* _Ab = (base);                                                \
            char* _Bb = (base) + ABYTES;                                       \
            _Pragma("unroll")                                                  \
            for (int _kk = 0; _kk < 2; ++_kk){                                 \
                bf16x8 _af[2], _bf[3];                                         \
                _Pragma("unroll")                                              \
                for (int _m = 0; _m < 2; ++_m){                                \
                    int _r  = wr*32 + _m*16 + s;                               \
                    _af[_m] = *(const bf16x8*)(_Ab + _r*A_STRIDE               \
                                               + (_kk*4 + g)*16);              \
                }                                                              \
                _Pragma("unroll")                                              \
                for (int _n = 0; _n < 3; ++_n){                                \
                    int _r  = wc*48 + _n*16 + s;                               \
                    int _ch = _r*8 + ((_kk*4 + g) ^ (_r & 7));                 \
                    _bf[_n] = *(const bf16x8*)(_Bb + _ch*16);                  \
                }                                                              \
                __builtin_amdgcn_s_setprio(1);                                 \
                _Pragma("unroll")                                              \
                for (int _m = 0; _m < 2; ++_m)                                 \
                    _Pragma("unroll")                                          \
                    for (int _n = 0; _n < 3; ++_n)                             \
                        accv[_m][_n] = __builtin_amdgcn_mfma_f32_16x16x32_bf16(\
                            _af[_m], _bf[_n], accv[_m][_n], 0, 0, 0);          \
                __builtin_amdgcn_s_setprio(0);                                 \
            }                                                                  \
        } while (0)

        __builtin_amdgcn_s_barrier();          // tile 0 published
        for (int t = 0; t < NT; ++t){
            COMPUTE(r0);
            __builtin_amdgcn_s_barrier();      // tile t+1 published
            ROT();
        }
        // epilogue: (pred - isum)^2
        #pragma unroll
        for (int m = 0; m < 2; ++m){
            int rbase = m0 + wr*32 + m*16 + g*4;
            #pragma unroll
            for (int n = 0; n < 3; ++n){
                int col = n0 + wc*48 + n*16 + s;
                #pragma unroll
                for (int jj = 0; jj < 4; ++jj){
                    float is = bf2f(isum[(size_t)(rbase+jj)*OUT_F + col]);
                    float d = accv[m][n][jj] - is;
                    local += d*d;
                }
            }
        }
    } else if (w < 6){
        // ================= B-stager waves (gload16, XOR-swizzled src) =======
        const int p  = w - 4;                  // 0..1, 6 chunks each
        const int lr = l >> 3;                 // row within 8-row chunk
        const int lc = l & 7;                  // 16B column
        #define BSTAGE(kt, base) do {                                          \
            _Pragma("unroll")                                                  \
            for (int _i = 0; _i < 6; ++_i){                                    \
                int _c   = p*6 + _i;                                           \
                int _row = _c*8 + lr;                                          \
                int _csw = ((lc ^ (_row & 7)) << 3);                           \
                gload16(bt + (size_t)(n0 + _row)*IN_F + _csw + (size_t)(kt)*BK,\
                        (base) + ABYTES + _c*1024);                            \
            }                                                                  \
        } while (0)

        BSTAGE(0, r0); BSTAGE(1, r1);
        WAITV(6);                              // tile 0's B landed
        __builtin_amdgcn_s_barrier();
        for (int t = 0; t < NT; ++t){
            if (t + 2 < NT) { BSTAGE(t+2, r2); WAITV(6); }
            else if (t == NT-2) { WAITV(0); }
            __builtin_amdgcn_s_barrier();
            ROT();
        }
    } else {
        // ================= A-stager waves: f32 load -> cvt -> ds_write ======
        const int ar = (w - 6)*32 + (l >> 1);  // row 0..63 in tile
        const int ah = l & 1;                  // half: f32 cols ah*32..+31
        const float* aSrc = lat + (size_t)(m0 + ar)*IN_F + ah*32;
        const int   aOff  = ar*A_STRIDE + ah*64;

        f32x4 sA0[8], sA1[8];
        #define AISSUE(kt, SET) do {                                           \
            const f32x4* _p = (const f32x4*)(aSrc + (size_t)(kt)*BK);          \
            _Pragma("unroll")                                                  \
            for (int _j = 0; _j < 8; ++_j) SET[_j] = _p[_j];                   \
        } while (0)

        #define ACOMMIT(SET, dstbuf) do {                                      \
            uint32_t _wd[16];                                                  \
            _Pragma("unroll")                                                  \
            for (int _j = 0; _j < 16; ++_j){                                   \
                float _lo = SET[_j >> 1][2*(_j & 1)];                          \
                float _hi = SET[_j >> 1][2*(_j & 1) + 1];                      \
                asm("v_cvt_pk_bf16_f32 %0, %1, %2"                             \
                    : "=v"(_wd[_j]) : "v"(_lo), "v"(_hi));                     \
            }                                                                  \
            char* _d = (dstbuf) + aOff;                                        \
            _Pragma("unroll")                                                  \
            for (int _q = 0; _q < 4; ++_q)                                     \
                *(int4*)(_d + _q*16) = *(const int4*)&_wd[_q*4];               \
        } while (0)

        AISSUE(0, sA0); AISSUE(1, sA1);        // tile u -> set[u&1]
        WAITV(8);                              // tile 0 regs ready
        ACOMMIT(sA0, r0);
        LGKM0();
        __builtin_amdgcn_s_barrier();          // publish tile 0
        for (int tp = 0; tp < 31; ++tp){
            // t = 2tp: issue tile t+2 -> sA0 ; commit tile t+1 (sA1) -> r1
            AISSUE(2*tp + 2, sA0);
            WAITV(8);
            ACOMMIT(sA1, r1);
            LGKM0();
            __builtin_amdgcn_s_barrier();
            ROT();
            // t = 2tp+1: issue tile t+2 -> sA1 ; commit tile t+1 (sA0) -> r1
            AISSUE(2*tp + 3, sA1);
            WAITV(8);
            ACOMMIT(sA0, r1);
            LGKM0();
            __builtin_amdgcn_s_barrier();
            ROT();
        }
        // t = 62: no issue; commit tile 63 (sA1) -> r1
        WAITV(0);
        ACOMMIT(sA1, r1);
        LGKM0();
        __builtin_amdgcn_s_barrier();
        ROT();
        // t = 63: compute-only step
        __builtin_amdgcn_s_barrier();
        ROT();
    }

    // block-level loss partial (producers contribute 0)
    #pragma unroll
    for (int off = 32; off; off >>= 1) local += __shfl_down(local, off);
    if (l == 0) part[w] = local;
    __syncthreads();
    if (tid == 0){
        float ssum = 0.f;
        #pragma unroll
        for (int i = 0; i < 8; ++i) ssum += part[i];
        lossp[bid] = ssum;
    }
}

// ------- kernel 3: finalize (deterministic partial-sum reduce) ---------------
__launch_bounds__(256)
__global__ void finalize(const float* __restrict__ lossp,
                         const float* __restrict__ polp,
                         float* __restrict__ out){
    __shared__ float sm[2][4];
    const int tid = threadIdx.x;
    float a = 0.f, b = 0.f;
    #pragma unroll
    for (int i = tid; i < 512; i += 256) a += lossp[i];
    #pragma unroll
    for (int i = tid; i < 768; i += 256) b += polp[i];
    #pragma unroll
    for (int off = 32; off; off >>= 1){
        a += __shfl_down(a, off);
        b += __shfl_down(b, off);
    }
    if ((tid & 63) == 0){ sm[0][tid >> 6] = a; sm[1][tid >> 6] = b; }
    __syncthreads();
    if (tid == 0){
        float sa = sm[0][0]+sm[0][1]+sm[0][2]+sm[0][3];
        float sb = sm[1][0]+sm[1][1]+sm[1][2]+sm[1][3];
        out[0] = sa * (1.0f / ((float)BATCH * (float)OUT_F * 128.0f));
        out[1] = sb * (1.0f / ((float)IN_F * (float)WCOLS));
    }
}

extern "C" void kernel_launch(void* const* d_in, const int* in_sizes, int n_in,
                              void* d_out, int out_size, void* d_ws, size_t ws_size,
                              hipStream_t stream){
    const float* latent   = (const float*)d_in[0];
    const float* true_sum = (const float*)d_in[1];
    const float* weight   = (const float*)d_in[2];
    float* lossp = (float*)d_ws;                              // 512 floats
    float* polp  = (float*)((char*)d_ws + 4096);              // 768 floats
    unsigned short* bt   = (unsigned short*)((char*)d_ws + 16384);
    unsigned short* isum = (unsigned short*)((char*)d_ws + 16384
                                             + (size_t)OUT_F*IN_F*2);
    float* out = (float*)d_out;

    decode_all<<<768 + 2048, 256, 0, stream>>>(weight, true_sum, bt, isum, polp);
    gemm_loss<<<(BATCH/BM)*(OUT_F/BN), 512, 0, stream>>>(latent, bt, isum, lossp);
    finalize<<<1, 256, 0, stream>>>(lossp, polp, out);
}

// Round 7
// 109.793 us; speedup vs baseline: 1.0354x; 1.0354x over previous
//
#include <hip/hip_runtime.h>
#include <stdint.h>

#define IN_F   4096
#define OUT_F  768
#define NB     8
#define BATCH  4096
#define WCOLS  (OUT_F*NB)   // 6144
#define PREDN  (BATCH*OUT_F) // 3145728

typedef short  bf16x8  __attribute__((ext_vector_type(8)));
typedef float  f32x4   __attribute__((ext_vector_type(4)));
typedef unsigned short ushort8 __attribute__((ext_vector_type(8)));

__device__ __forceinline__ unsigned short f2bf(float f){
    union { float f; uint32_t u; } v; v.f = f;
    uint32_t u = v.u;
    u += 0x7FFFu + ((u >> 16) & 1u);   // round-to-nearest-even
    return (unsigned short)(u >> 16);
}

__device__ __forceinline__ void gload16(const void* g, void* l){
    __builtin_amdgcn_global_load_lds(
        (const __attribute__((address_space(1))) unsigned int*)g,
        (__attribute__((address_space(3))) unsigned int*)l, 16, 0, 0);
}

// ------- kernel 1: weight-decode (-> bt, polp) + latent f32->bf16 cast ------
__launch_bounds__(256)
__global__ void decode_all(const float* __restrict__ w,
                           const float* __restrict__ lat,
                           unsigned short* __restrict__ bt,
                           unsigned short* __restrict__ abf,
                           float* __restrict__ polp){
    __shared__ unsigned short tile[64][70];
    __shared__ float part[4];
    const int tid = threadIdx.x;
    const int bid = blockIdx.x;
    if (bid < 768){
        // ---- sigmoid-decode weight -> int_weights^T (bf16) ----
        const int k0 = (bid & 63) * 64;
        const int n0 = (bid >> 6) * 64;
        const int j     = tid & 63;
        const int ibase = (tid >> 6) * 16;
        float pol = 0.f;
        #pragma unroll 4
        for (int r = 0; r < 16; ++r){
            int i = ibase + r;
            const float4* src = (const float4*)(w + (size_t)(k0+i)*WCOLS + (size_t)(n0+j)*8);
            float4 a = src[0], b = src[1];
            float x[8] = {a.x,a.y,a.z,a.w,b.x,b.y,b.z,b.w};
            float p[8];
            #pragma unroll
            for (int q = 0; q < 8; ++q){
                p[q] = 1.f / (1.f + __expf(-x[q]));
                pol += p[q] * (1.f - p[q]);
            }
            float iw = p[0] + 2.f*p[1] + 4.f*p[2] + 8.f*p[3]
                     + 16.f*p[4] + 32.f*p[5] + 64.f*p[6] - 128.f*p[7];
            tile[j][i] = f2bf(iw);
        }
        #pragma unroll
        for (int off = 32; off; off >>= 1) pol += __shfl_down(pol, off);
        if ((tid & 63) == 0) part[tid >> 6] = pol;
        __syncthreads();
        const int nrow = tid >> 4;
        const int kb   = (tid & 15) * 4;
        #pragma unroll
        for (int q = 0; q < 4; ++q){
            int n = nrow + q*16;
            uint2 v;
            v.x = *(const unsigned int*)&tile[n][kb];
            v.y = *(const unsigned int*)&tile[n][kb+2];
            *(uint2*)(bt + (size_t)(n0+n)*IN_F + k0 + kb) = v;
        }
        if (tid == 0) polp[bid] = part[0]+part[1]+part[2]+part[3];
    } else {
        // ---- latent f32 -> bf16 ----
        int idx = ((bid - 768) * 256 + tid) * 8;
        const float4* p = (const float4*)(lat + idx);
        float4 a = p[0], b = p[1];
        ushort8 o;
        o[0]=f2bf(a.x); o[1]=f2bf(a.y); o[2]=f2bf(a.z); o[3]=f2bf(a.w);
        o[4]=f2bf(b.x); o[5]=f2bf(b.y); o[6]=f2bf(b.z); o[7]=f2bf(b.w);
        *(ushort8*)(abf + idx) = o;
    }
}

// ------- kernel 2: bf16 GEMM, 128x96 tile, K-split x2, m97 loop -------------
#define BM 128
#define BN 96
#define BK 64
#define NTH 32                     // K-steps per half (K=2048)
#define ABYTES (BM*BK*2)           // 16384
#define BBYTES (BN*BK*2)           // 12288
#define BUFB   (ABYTES+BBYTES)     // 28672

__launch_bounds__(256)
__global__ void gemm_pred(const unsigned short* __restrict__ abf,
                          const unsigned short* __restrict__ bt,
                          float* __restrict__ pred){
    __shared__ __align__(16) char smem[2*BUFB];   // 56 KB -> 2 blocks/CU
    const int tid = threadIdx.x;
    const int w   = tid >> 6;
    const int l   = tid & 63;
    const int s   = l & 15, g = l >> 4;
    const int wr  = w >> 1, wc = w & 1;    // 2x2 waves, wave tile 64x48
    const int bid  = blockIdx.x;
    const int half = bid >> 8;             // K-half
    const int rem  = bid & 255;
    const int m0   = (rem >> 3) * BM;
    const int n0   = (rem & 7)  * BN;      // bid&7 == n-panel -> XCD-stable
    const int kb   = half * (NTH*BK);

    f32x4 accv[4][3];
    #pragma unroll
    for (int m = 0; m < 4; ++m)
        #pragma unroll
        for (int n = 0; n < 3; ++n)
            accv[m][n] = (f32x4){0.f,0.f,0.f,0.f};

    // staging: thread t covers rows r0+32i, 16B chunk col t&7 (linear LDS
    // dest); source chunk XOR-swizzled to match swizzled ds_reads
    const int c8  = tid & 7;
    const int r0  = tid >> 3;                    // 0..31; (r0+32i)&7 == r0&7
    const int scw = ((c8 ^ (r0 & 7)) << 3);
    const unsigned short* aS = abf + (size_t)(m0 + r0) * IN_F + kb + scw;
    const unsigned short* bS = bt  + (size_t)(n0 + r0) * IN_F + kb + scw;

    #define STAGE(kt, base) do {                                           \
        const int _ko = (kt) * BK;                                         \
        char* _ad = (base) + tid*16;                                       \
        char* _bd = (base) + ABYTES + tid*16;                              \
        _Pragma("unroll")                                                  \
        for (int _i = 0; _i < 4; ++_i)                                     \
            gload16(aS + (size_t)_i*32*IN_F + _ko, _ad + _i*4096);         \
        _Pragma("unroll")                                                  \
        for (int _i = 0; _i < 3; ++_i)                                     \
            gload16(bS + (size_t)_i*32*IN_F + _ko, _bd + _i*4096);         \
    } while (0)

    #define COMPUTE(base) do {                                             \
        char* _Ab = (base);                                                \
        char* _Bb = (base) + ABYTES;                                       \
        _Pragma("unroll")                                                  \
        for (int _kk = 0; _kk < 2; ++_kk){                                 \
            bf16x8 _af[4], _bf[3];                                         \
            _Pragma("unroll")                                              \
            for (int _m = 0; _m < 4; ++_m){                                \
                int _r  = wr*64 + _m*16 + s;                               \
                int _ch = _r*8 + ((_kk*4 + g) ^ (_r & 7));                 \
                _af[_m] = *(const bf16x8*)(_Ab + _ch*16);                  \
            }                                                              \
            _Pragma("unroll")                                              \
            for (int _n = 0; _n < 3; ++_n){                                \
                int _r  = wc*48 + _n*16 + s;                               \
                int _ch = _r*8 + ((_kk*4 + g) ^ (_r & 7));                 \
                _bf[_n] = *(const bf16x8*)(_Bb + _ch*16);                  \
            }                                                              \
            __builtin_amdgcn_s_setprio(1);                                 \
            _Pragma("unroll")                                              \
            for (int _m = 0; _m < 4; ++_m)                                 \
                _Pragma("unroll")                                          \
                for (int _n = 0; _n < 3; ++_n)                             \
                    accv[_m][_n] = __builtin_amdgcn_mfma_f32_16x16x32_bf16(\
                        _af[_m], _bf[_n], accv[_m][_n], 0, 0, 0);          \
            __builtin_amdgcn_s_setprio(0);                                 \
        }                                                                  \
    } while (0)

    // m97 loop: 2 buffers, one __syncthreads per step; the co-resident
    // block on the CU covers the vmcnt drain.
    char* b0 = smem;
    char* b1 = smem + BUFB;
    STAGE(0, b0);
    __syncthreads();
    for (int t = 0; t < NTH; ++t){
        if (t + 1 < NTH) STAGE(t + 1, (t & 1) ? b0 : b1);
        COMPUTE((t & 1) ? b1 : b0);
        __syncthreads();
    }

    // write partial-pred slab (f32)
    float* slab = pred + (size_t)half * PREDN;
    #pragma unroll
    for (int m = 0; m < 4; ++m){
        int rbase = m0 + wr*64 + m*16 + g*4;
        #pragma unroll
        for (int n = 0; n < 3; ++n){
            int col = n0 + wc*48 + n*16 + s;
            #pragma unroll
            for (int jj = 0; jj < 4; ++jj)
                slab[(size_t)(rbase+jj)*OUT_F + col] = accv[m][n][jj];
        }
    }
}

// ------- kernel 3: loss pass: pred slabs + raw ts decode -> lossp -----------
__launch_bounds__(256)
__global__ void loss_pass(const float* __restrict__ pred,
                          const float* __restrict__ ts,
                          float* __restrict__ lossp){
    __shared__ float part[4];
    const int tid = threadIdx.x;
    const int e0  = (blockIdx.x * 256 + tid) * 2;
    float local = 0.f;
    #pragma unroll
    for (int q = 0; q < 2; ++q){
        int e = e0 + q;
        float p = pred[e] + pred[(size_t)PREDN + e];
        const float4* r = (const float4*)(ts + (size_t)e * 8);
        float4 x = r[0], y = r[1];
        float is = x.x + 2.f*x.y + 4.f*x.z + 8.f*x.w
                 + 16.f*y.x + 32.f*y.y + 64.f*y.z - 128.f*y.w;
        float d = p - is;
        local += d*d;
    }
    #pragma unroll
    for (int off = 32; off; off >>= 1) local += __shfl_down(local, off);
    if ((tid & 63) == 0) part[tid >> 6] = local;
    __syncthreads();
    if (tid == 0) lossp[blockIdx.x] = part[0]+part[1]+part[2]+part[3];
}

// ------- kernel 4: finalize -------------------------------------------------
__launch_bounds__(256)
__global__ void finalize(const float* __restrict__ lossp,
                         const float* __restrict__ polp,
                         float* __restrict__ out){
    __shared__ float sm[2][4];
    const int tid = threadIdx.x;
    float a = 0.f, b = 0.f;
    for (int i = tid; i < 6144; i += 256) a += lossp[i];
    for (int i = tid; i < 768;  i += 256) b += polp[i];
    #pragma unroll
    for (int off = 32; off; off >>= 1){
        a += __shfl_down(a, off);
        b += __shfl_down(b, off);
    }
    if ((tid & 63) == 0){ sm[0][tid >> 6] = a; sm[1][tid >> 6] = b; }
    __syncthreads();
    if (tid == 0){
        float sa = sm[0][0]+sm[0][1]+sm[0][2]+sm[0][3];
        float sb = sm[1][0]+sm[1][1]+sm[1][2]+sm[1][3];
        out[0] = sa * (1.0f / ((float)BATCH * (float)OUT_F * 128.0f));
        out[1] = sb * (1.0f / ((float)IN_F * (float)WCOLS));
    }
}

extern "C" void kernel_launch(void* const* d_in, const int* in_sizes, int n_in,
                              void* d_out, int out_size, void* d_ws, size_t ws_size,
                              hipStream_t stream){
    const float* latent   = (const float*)d_in[0];
    const float* true_sum = (const float*)d_in[1];
    const float* weight   = (const float*)d_in[2];
    char* ws = (char*)d_ws;
    float* lossp = (float*)ws;                                  // 24 KB
    float* polp  = (float*)(ws + 32768);                        // 3 KB
    unsigned short* bt  = (unsigned short*)(ws + 65536);        // 6 MB
    unsigned short* abf = (unsigned short*)(ws + 65536 + 6291456);      // 32 MB
    float* pred = (float*)(ws + 65536 + 6291456 + 33554432);    // 2x12.6 MB
    float* out = (float*)d_out;

    decode_all<<<768 + 8192, 256, 0, stream>>>(weight, latent, bt, abf, polp);
    gemm_pred<<<512, 256, 0, stream>>>(abf, bt, pred);
    loss_pass<<<PREDN/512, 256, 0, stream>>>(pred, true_sum, lossp);
    finalize<<<1, 256, 0, stream>>>(lossp, polp, out);
}

// Round 8
// 109.657 us; speedup vs baseline: 1.0367x; 1.0012x over previous
//
#include <hip/hip_runtime.h>
#include <stdint.h>

#define IN_F   4096
#define OUT_F  768
#define NB     8
#define BATCH  4096
#define WCOLS  (OUT_F*NB)   // 6144
#define PREDN  (BATCH*OUT_F) // 3145728

typedef short  bf16x8  __attribute__((ext_vector_type(8)));
typedef float  f32x4   __attribute__((ext_vector_type(4)));
typedef unsigned short ushort8 __attribute__((ext_vector_type(8)));

__device__ __forceinline__ unsigned short f2bf(float f){
    union { float f; uint32_t u; } v; v.f = f;
    uint32_t u = v.u;
    u += 0x7FFFu + ((u >> 16) & 1u);   // round-to-nearest-even
    return (unsigned short)(u >> 16);
}

__device__ __forceinline__ void gload16(const void* g, void* l){
    __builtin_amdgcn_global_load_lds(
        (const __attribute__((address_space(1))) unsigned int*)g,
        (__attribute__((address_space(3))) unsigned int*)l, 16, 0, 0);
}

// ------- kernel 1: weight-decode (-> bt, polp) + latent f32->bf16 cast ------
// Both paths restructured for memory-level parallelism (loads issued in
// groups BEFORE dependent compute) — round 7 showed latency-bound (hbm 23%,
// VALU 20%).
__launch_bounds__(256)
__global__ void decode_all(const float* __restrict__ w,
                           const float* __restrict__ lat,
                           unsigned short* __restrict__ bt,
                           unsigned short* __restrict__ abf,
                           float* __restrict__ polp){
    __shared__ unsigned short tile[64][70];
    __shared__ float part[4];
    const int tid = threadIdx.x;
    const int bid = blockIdx.x;
    if (bid < 768){
        // ---- sigmoid-decode weight -> int_weights^T (bf16) ----
        const int k0 = (bid & 63) * 64;
        const int n0 = (bid >> 6) * 64;
        const int j     = tid & 63;
        const int ibase = (tid >> 6) * 16;
        float pol = 0.f;
        #pragma unroll
        for (int grp = 0; grp < 4; ++grp){
            // issue 8 16B loads (4 rows x 2) before any compute
            float4 va[4][2];
            #pragma unroll
            for (int r = 0; r < 4; ++r){
                int i = ibase + grp*4 + r;
                const float4* src = (const float4*)(w + (size_t)(k0+i)*WCOLS
                                                      + (size_t)(n0+j)*8);
                va[r][0] = src[0];
                va[r][1] = src[1];
            }
            #pragma unroll
            for (int r = 0; r < 4; ++r){
                float x[8] = {va[r][0].x, va[r][0].y, va[r][0].z, va[r][0].w,
                              va[r][1].x, va[r][1].y, va[r][1].z, va[r][1].w};
                float p[8];
                #pragma unroll
                for (int q = 0; q < 8; ++q){
                    // fast sigmoid: v_rcp (1 inst) instead of precise divide
                    p[q] = __builtin_amdgcn_rcpf(1.f + __expf(-x[q]));
                    pol += p[q] * (1.f - p[q]);
                }
                float iw = p[0] + 2.f*p[1] + 4.f*p[2] + 8.f*p[3]
                         + 16.f*p[4] + 32.f*p[5] + 64.f*p[6] - 128.f*p[7];
                tile[j][ibase + grp*4 + r] = f2bf(iw);
            }
        }
        #pragma unroll
        for (int off = 32; off; off >>= 1) pol += __shfl_down(pol, off);
        if ((tid & 63) == 0) part[tid >> 6] = pol;
        __syncthreads();
        const int nrow = tid >> 4;
        const int kb   = (tid & 15) * 4;
        #pragma unroll
        for (int q = 0; q < 4; ++q){
            int n = nrow + q*16;
            uint2 v;
            v.x = *(const unsigned int*)&tile[n][kb];
            v.y = *(const unsigned int*)&tile[n][kb+2];
            *(uint2*)(bt + (size_t)(n0+n)*IN_F + k0 + kb) = v;
        }
        if (tid == 0) polp[bid] = part[0]+part[1]+part[2]+part[3];
    } else {
        // ---- latent f32 -> bf16, 16 floats/thread, 4 loads in flight ----
        const int base = ((bid - 768) * 256 + tid) * 16;
        const float4* p = (const float4*)(lat + base);
        float4 v0 = p[0], v1 = p[1], v2 = p[2], v3 = p[3];
        ushort8 o0, o1;
        o0[0]=f2bf(v0.x); o0[1]=f2bf(v0.y); o0[2]=f2bf(v0.z); o0[3]=f2bf(v0.w);
        o0[4]=f2bf(v1.x); o0[5]=f2bf(v1.y); o0[6]=f2bf(v1.z); o0[7]=f2bf(v1.w);
        o1[0]=f2bf(v2.x); o1[1]=f2bf(v2.y); o1[2]=f2bf(v2.z); o1[3]=f2bf(v2.w);
        o1[4]=f2bf(v3.x); o1[5]=f2bf(v3.y); o1[6]=f2bf(v3.z); o1[7]=f2bf(v3.w);
        *(ushort8*)(abf + base)     = o0;
        *(ushort8*)(abf + base + 8) = o1;
    }
}

// ------- kernel 2: bf16 GEMM, 128x96 tile, K-split x2, m97 loop -------------
#define BM 128
#define BN 96
#define BK 64
#define NTH 32                     // K-steps per half (K=2048)
#define ABYTES (BM*BK*2)           // 16384
#define BBYTES (BN*BK*2)           // 12288
#define BUFB   (ABYTES+BBYTES)     // 28672

__launch_bounds__(256)
__global__ void gemm_pred(const unsigned short* __restrict__ abf,
                          const unsigned short* __restrict__ bt,
                          float* __restrict__ pred){
    __shared__ __align__(16) char smem[2*BUFB];   // 56 KB -> 2 blocks/CU
    const int tid = threadIdx.x;
    const int w   = tid >> 6;
    const int l   = tid & 63;
    const int s   = l & 15, g = l >> 4;
    const int wr  = w >> 1, wc = w & 1;    // 2x2 waves, wave tile 64x48
    const int bid  = blockIdx.x;
    const int half = bid >> 8;             // K-half
    const int rem  = bid & 255;
    const int m0   = (rem >> 3) * BM;
    const int n0   = (rem & 7)  * BN;      // bid&7 == n-panel -> XCD-stable
    const int kb   = half * (NTH*BK);

    f32x4 accv[4][3];
    #pragma unroll
    for (int m = 0; m < 4; ++m)
        #pragma unroll
        for (int n = 0; n < 3; ++n)
            accv[m][n] = (f32x4){0.f,0.f,0.f,0.f};

    const int c8  = tid & 7;
    const int r0  = tid >> 3;                    // 0..31; (r0+32i)&7 == r0&7
    const int scw = ((c8 ^ (r0 & 7)) << 3);
    const unsigned short* aS = abf + (size_t)(m0 + r0) * IN_F + kb + scw;
    const unsigned short* bS = bt  + (size_t)(n0 + r0) * IN_F + kb + scw;

    #define STAGE(kt, base) do {                                           \
        const int _ko = (kt) * BK;                                         \
        char* _ad = (base) + tid*16;                                       \
        char* _bd = (base) + ABYTES + tid*16;                              \
        _Pragma("unroll")                                                  \
        for (int _i = 0; _i < 4; ++_i)                                     \
            gload16(aS + (size_t)_i*32*IN_F + _ko, _ad + _i*4096);         \
        _Pragma("unroll")                                                  \
        for (int _i = 0; _i < 3; ++_i)                                     \
            gload16(bS + (size_t)_i*32*IN_F + _ko, _bd + _i*4096);         \
    } while (0)

    #define COMPUTE(base) do {                                             \
        char* _Ab = (base);                                                \
        char* _Bb = (base) + ABYTES;                                       \
        _Pragma("unroll")                                                  \
        for (int _kk = 0; _kk < 2; ++_kk){                                 \
            bf16x8 _af[4], _bf[3];                                         \
            _Pragma("unroll")                                              \
            for (int _m = 0; _m < 4; ++_m){                                \
                int _r  = wr*64 + _m*16 + s;                               \
                int _ch = _r*8 + ((_kk*4 + g) ^ (_r & 7));                 \
                _af[_m] = *(const bf16x8*)(_Ab + _ch*16);                  \
            }                                                              \
            _Pragma("unroll")                                              \
            for (int _n = 0; _n < 3; ++_n){                                \
                int _r  = wc*48 + _n*16 + s;                               \
                int _ch = _r*8 + ((_kk*4 + g) ^ (_r & 7));                 \
                _bf[_n] = *(const bf16x8*)(_Bb + _ch*16);                  \
            }                                                              \
            __builtin_amdgcn_s_setprio(1);                                 \
            _Pragma("unroll")                                              \
            for (int _m = 0; _m < 4; ++_m)                                 \
                _Pragma("unroll")                                          \
                for (int _n = 0; _n < 3; ++_n)                             \
                    accv[_m][_n] = __builtin_amdgcn_mfma_f32_16x16x32_bf16(\
                        _af[_m], _bf[_n], accv[_m][_n], 0, 0, 0);          \
            __builtin_amdgcn_s_setprio(0);                                 \
        }                                                                  \
    } while (0)

    char* b0 = smem;
    char* b1 = smem + BUFB;
    STAGE(0, b0);
    __syncthreads();
    for (int t = 0; t < NTH; ++t){
        if (t + 1 < NTH) STAGE(t + 1, (t & 1) ? b0 : b1);
        COMPUTE((t & 1) ? b1 : b0);
        __syncthreads();
    }

    float* slab = pred + (size_t)half * PREDN;
    #pragma unroll
    for (int m = 0; m < 4; ++m){
        int rbase = m0 + wr*64 + m*16 + g*4;
        #pragma unroll
        for (int n = 0; n < 3; ++n){
            int col = n0 + wc*48 + n*16 + s;
            #pragma unroll
            for (int jj = 0; jj < 4; ++jj)
                slab[(size_t)(rbase+jj)*OUT_F + col] = accv[m][n][jj];
        }
    }
}

// ------- kernel 3: loss pass: pred slabs + raw ts decode -> lossp -----------
// 4 elements/thread; all loads issued before compute (MLP).
__launch_bounds__(256)
__global__ void loss_pass(const float* __restrict__ pred,
                          const float* __restrict__ ts,
                          float* __restrict__ lossp){
    __shared__ float part[4];
    const int tid = threadIdx.x;
    const int e0  = (blockIdx.x * 256 + tid) * 4;
    // issue: 2 pred float4 + 8 ts float4
    const float4 p0 = *(const float4*)(pred + e0);
    const float4 p1 = *(const float4*)(pred + (size_t)PREDN + e0);
    float4 t[8];
    const float4* r = (const float4*)(ts + (size_t)e0 * 8);
    #pragma unroll
    for (int i = 0; i < 8; ++i) t[i] = r[i];
    float local = 0.f;
    #pragma unroll
    for (int q = 0; q < 4; ++q){
        float4 x = t[2*q], y = t[2*q+1];
        float is = x.x + 2.f*x.y + 4.f*x.z + 8.f*x.w
                 + 16.f*y.x + 32.f*y.y + 64.f*y.z - 128.f*y.w;
        float pv = (q==0) ? (p0.x+p1.x) : (q==1) ? (p0.y+p1.y)
                 : (q==2) ? (p0.z+p1.z) : (p0.w+p1.w);
        float d = pv - is;
        local += d*d;
    }
    #pragma unroll
    for (int off = 32; off; off >>= 1) local += __shfl_down(local, off);
    if ((tid & 63) == 0) part[tid >> 6] = local;
    __syncthreads();
    if (tid == 0) lossp[blockIdx.x] = part[0]+part[1]+part[2]+part[3];
}

// ------- kernel 4: finalize -------------------------------------------------
__launch_bounds__(256)
__global__ void finalize(const float* __restrict__ lossp,
                         const float* __restrict__ polp,
                         float* __restrict__ out){
    __shared__ float sm[2][4];
    const int tid = threadIdx.x;
    float a = 0.f, b = 0.f;
    for (int i = tid; i < 3072; i += 256) a += lossp[i];
    for (int i = tid; i < 768;  i += 256) b += polp[i];
    #pragma unroll
    for (int off = 32; off; off >>= 1){
        a += __shfl_down(a, off);
        b += __shfl_down(b, off);
    }
    if ((tid & 63) == 0){ sm[0][tid >> 6] = a; sm[1][tid >> 6] = b; }
    __syncthreads();
    if (tid == 0){
        float sa = sm[0][0]+sm[0][1]+sm[0][2]+sm[0][3];
        float sb = sm[1][0]+sm[1][1]+sm[1][2]+sm[1][3];
        out[0] = sa * (1.0f / ((float)BATCH * (float)OUT_F * 128.0f));
        out[1] = sb * (1.0f / ((float)IN_F * (float)WCOLS));
    }
}

extern "C" void kernel_launch(void* const* d_in, const int* in_sizes, int n_in,
                              void* d_out, int out_size, void* d_ws, size_t ws_size,
                              hipStream_t stream){
    const float* latent   = (const float*)d_in[0];
    const float* true_sum = (const float*)d_in[1];
    const float* weight   = (const float*)d_in[2];
    char* ws = (char*)d_ws;
    float* lossp = (float*)ws;                                  // 12 KB
    float* polp  = (float*)(ws + 32768);                        // 3 KB
    unsigned short* bt  = (unsigned short*)(ws + 65536);        // 6 MB
    unsigned short* abf = (unsigned short*)(ws + 65536 + 6291456);      // 32 MB
    float* pred = (float*)(ws + 65536 + 6291456 + 33554432);    // 2x12.6 MB
    float* out = (float*)d_out;

    decode_all<<<768 + 4096, 256, 0, stream>>>(weight, latent, bt, abf, polp);
    gemm_pred<<<512, 256, 0, stream>>>(abf, bt, pred);
    loss_pass<<<PREDN/1024, 256, 0, stream>>>(pred, true_sum, lossp);
    finalize<<<1, 256, 0, stream>>>(lossp, polp, out);
}